// Round 2
// baseline (1389.131 us; speedup 1.0000x reference)
//
#include <hip/hip_runtime.h>
#include <math.h>

// Problem constants
constexpr int Bv = 4, Lv = 2048, Cv = 512, Hv = 8, CHv = 64;
constexpr int Mv = Bv * Lv;      // 8192 rows
constexpr int N3 = 3 * Cv;       // 1536
constexpr float EPSv = 1e-5f;
constexpr float SCALEv = 0.125f; // 1/sqrt(64)

// ---------------- LayerNorm: one wave per 512-float row ----------------
__global__ __launch_bounds__(256) void ln_kernel(const float* __restrict__ x,
                                                 const float* __restrict__ gamma,
                                                 const float* __restrict__ beta,
                                                 float* __restrict__ xn) {
  const int row = blockIdx.x * 4 + (threadIdx.x >> 6);
  const int lane = threadIdx.x & 63;
  const float4* xr = reinterpret_cast<const float4*>(x + (size_t)row * Cv);
  float4 v0 = xr[lane];
  float4 v1 = xr[lane + 64];
  float s = v0.x + v0.y + v0.z + v0.w + v1.x + v1.y + v1.z + v1.w;
  float q = v0.x * v0.x + v0.y * v0.y + v0.z * v0.z + v0.w * v0.w +
            v1.x * v1.x + v1.y * v1.y + v1.z * v1.z + v1.w * v1.w;
#pragma unroll
  for (int m = 1; m < 64; m <<= 1) {
    s += __shfl_xor(s, m, 64);
    q += __shfl_xor(q, m, 64);
  }
  const float mu = s * (1.0f / Cv);
  const float var = q * (1.0f / Cv) - mu * mu;
  const float rstd = rsqrtf(var + EPSv);
  const float4* g4 = reinterpret_cast<const float4*>(gamma);
  const float4* b4 = reinterpret_cast<const float4*>(beta);
  float4 ga = g4[lane], gb = g4[lane + 64];
  float4 ba = b4[lane], bb = b4[lane + 64];
  float4 o0, o1;
  o0.x = (v0.x - mu) * rstd * ga.x + ba.x;
  o0.y = (v0.y - mu) * rstd * ga.y + ba.y;
  o0.z = (v0.z - mu) * rstd * ga.z + ba.z;
  o0.w = (v0.w - mu) * rstd * ga.w + ba.w;
  o1.x = (v1.x - mu) * rstd * gb.x + bb.x;
  o1.y = (v1.y - mu) * rstd * gb.y + bb.y;
  o1.z = (v1.z - mu) * rstd * gb.z + bb.z;
  o1.w = (v1.w - mu) * rstd * gb.w + bb.w;
  float4* xo = reinterpret_cast<float4*>(xn + (size_t)row * Cv);
  xo[lane] = o0;
  xo[lane + 64] = o1;
}

// ---------------- fp32 GEMM: C = A(MxK) * B(KxN) + bias (+ residual) ----
// 128x128 tile, BK=16, 256 threads, 8x8 micro-tile split as 2x(4rows) x 2x(4cols)
// so LDS fragment reads are broadcast (A) / lane-stride-1 (B): conflict-free.
template <bool RES>
__global__ __launch_bounds__(256) void gemm128(const float* __restrict__ A,
                                               const float* __restrict__ Bm,
                                               const float* __restrict__ bias,
                                               const float* __restrict__ res,
                                               float* __restrict__ Cm,
                                               int M, int N, int K) {
  __shared__ float As[16][132]; // transposed A tile: As[k][m]
  __shared__ float Bs[16][132]; // natural B tile:    Bs[k][n]
  const int t = threadIdx.x;
  const int m0 = blockIdx.y * 128;
  const int n0 = blockIdx.x * 128;
  const int rg = t >> 4; // 0..15 row-group
  const int cg = t & 15; // 0..15 col-group
  const int ar = t >> 2; // A-load row 0..63 (and +64)
  const int af = t & 3;  // A-load f4 within K-16
  const int br = t >> 5; // B-load row 0..7 (and +8)
  const int bf = t & 31; // B-load f4 within N-128

  float acc[8][8];
#pragma unroll
  for (int i = 0; i < 8; ++i)
#pragma unroll
    for (int j = 0; j < 8; ++j) acc[i][j] = 0.0f;

  for (int k0 = 0; k0 < K; k0 += 16) {
    float4 a0 = *reinterpret_cast<const float4*>(A + (size_t)(m0 + ar) * K + k0 + af * 4);
    float4 a1 = *reinterpret_cast<const float4*>(A + (size_t)(m0 + ar + 64) * K + k0 + af * 4);
    float4 b0 = *reinterpret_cast<const float4*>(Bm + (size_t)(k0 + br) * N + n0 + bf * 4);
    float4 b1 = *reinterpret_cast<const float4*>(Bm + (size_t)(k0 + br + 8) * N + n0 + bf * 4);
    __syncthreads(); // previous iteration's LDS reads complete
    As[af * 4 + 0][ar] = a0.x;
    As[af * 4 + 1][ar] = a0.y;
    As[af * 4 + 2][ar] = a0.z;
    As[af * 4 + 3][ar] = a0.w;
    As[af * 4 + 0][ar + 64] = a1.x;
    As[af * 4 + 1][ar + 64] = a1.y;
    As[af * 4 + 2][ar + 64] = a1.z;
    As[af * 4 + 3][ar + 64] = a1.w;
    *reinterpret_cast<float4*>(&Bs[br][bf * 4]) = b0;
    *reinterpret_cast<float4*>(&Bs[br + 8][bf * 4]) = b1;
    __syncthreads();
#pragma unroll
    for (int kk = 0; kk < 16; ++kk) {
      float4 aA = *reinterpret_cast<const float4*>(&As[kk][rg * 4]);
      float4 aB = *reinterpret_cast<const float4*>(&As[kk][64 + rg * 4]);
      float4 bA = *reinterpret_cast<const float4*>(&Bs[kk][cg * 4]);
      float4 bB = *reinterpret_cast<const float4*>(&Bs[kk][64 + cg * 4]);
      float a[8] = {aA.x, aA.y, aA.z, aA.w, aB.x, aB.y, aB.z, aB.w};
      float bb_[8] = {bA.x, bA.y, bA.z, bA.w, bB.x, bB.y, bB.z, bB.w};
#pragma unroll
      for (int i = 0; i < 8; ++i)
#pragma unroll
        for (int j = 0; j < 8; ++j) acc[i][j] += a[i] * bb_[j];
    }
  }

  // epilogue: bias (+ residual), coalesced float4 stores
#pragma unroll
  for (int i = 0; i < 8; ++i) {
    const int row = m0 + rg * 4 + (i & 3) + (i >> 2) * 64;
#pragma unroll
    for (int jh = 0; jh < 2; ++jh) {
      const int col = n0 + cg * 4 + jh * 64;
      float4 c;
      c.x = acc[i][jh * 4 + 0] + bias[col + 0];
      c.y = acc[i][jh * 4 + 1] + bias[col + 1];
      c.z = acc[i][jh * 4 + 2] + bias[col + 2];
      c.w = acc[i][jh * 4 + 3] + bias[col + 3];
      if (RES) {
        float4 r = *reinterpret_cast<const float4*>(res + (size_t)row * N + col);
        c.x += r.x;
        c.y += r.y;
        c.z += r.z;
        c.w += r.w;
      }
      *reinterpret_cast<float4*>(Cm + (size_t)row * N + col) = c;
    }
  }
}

// ---------------- flash attention, fp32 ----------------
// block = 256 threads handles 64 q-rows of one (b,h); loops over 32 k-tiles of 64.
// K stored transposed in LDS (KT[ch][key]) so QK^T inner reads are stride-1.
__global__ __launch_bounds__(256) void attn_kernel(const float* __restrict__ qkv,
                                                   float* __restrict__ z) {
  __shared__ float Qs[64][68]; // [qrow][ch]
  __shared__ float KT[64][68]; // [ch][key]  (transposed)
  __shared__ float Vs[64][68]; // [key][ch]
  __shared__ float Ps[64][68]; // [qrow][key]
  const int t = threadIdx.x;
  const int qt = blockIdx.x, h = blockIdx.y, b = blockIdx.z;
  const int q0 = qt * 64;
  const float* base = qkv + (size_t)b * Lv * N3;
  const int qcol = h * CHv;
  const int kcol = Cv + h * CHv;
  const int vcol = 2 * Cv + h * CHv;

  const int lr = t >> 4; // load row base 0..15
  const int lf = t & 15; // load f4 col

// load Q tile once
#pragma unroll
  for (int u = 0; u < 4; ++u) {
    const int row = lr + u * 16;
    *reinterpret_cast<float4*>(&Qs[row][lf * 4]) =
        *reinterpret_cast<const float4*>(base + (size_t)(q0 + row) * N3 + qcol + lf * 4);
  }

  const int w = t >> 6;
  const int rg = (t >> 4) & 3;
  const int cg = t & 15;
  const int rbase = w * 16 + rg * 4; // this thread's 4 q-rows
  const int jbase = cg * 4;          // this thread's 4 keys (S) / 4 out-cols (PV)

  float acc[4][4] = {{0.f, 0.f, 0.f, 0.f}, {0.f, 0.f, 0.f, 0.f},
                     {0.f, 0.f, 0.f, 0.f}, {0.f, 0.f, 0.f, 0.f}};
  float mrow[4] = {-INFINITY, -INFINITY, -INFINITY, -INFINITY};
  float lrow[4] = {0.f, 0.f, 0.f, 0.f};

  for (int kt = 0; kt < Lv / 64; ++kt) {
    const int k0 = kt * 64;
    // prefetch K/V tile to registers
    float4 kvr[4], vvr[4];
#pragma unroll
    for (int u = 0; u < 4; ++u) {
      const int row = lr + u * 16;
      kvr[u] = *reinterpret_cast<const float4*>(base + (size_t)(k0 + row) * N3 + kcol + lf * 4);
      vvr[u] = *reinterpret_cast<const float4*>(base + (size_t)(k0 + row) * N3 + vcol + lf * 4);
    }
    __syncthreads(); // previous tile's LDS reads complete
#pragma unroll
    for (int u = 0; u < 4; ++u) {
      const int row = lr + u * 16;
      KT[lf * 4 + 0][row] = kvr[u].x;
      KT[lf * 4 + 1][row] = kvr[u].y;
      KT[lf * 4 + 2][row] = kvr[u].z;
      KT[lf * 4 + 3][row] = kvr[u].w;
      *reinterpret_cast<float4*>(&Vs[row][lf * 4]) = vvr[u];
    }
    __syncthreads();

    // S = Q K^T  (4x4 per thread)
    float s[4][4] = {{0.f, 0.f, 0.f, 0.f}, {0.f, 0.f, 0.f, 0.f},
                     {0.f, 0.f, 0.f, 0.f}, {0.f, 0.f, 0.f, 0.f}};
#pragma unroll
    for (int kk = 0; kk < 16; ++kk) {
      float4 qv[4], ktv[4];
#pragma unroll
      for (int i = 0; i < 4; ++i)
        qv[i] = *reinterpret_cast<const float4*>(&Qs[rbase + i][kk * 4]);
#pragma unroll
      for (int u = 0; u < 4; ++u)
        ktv[u] = *reinterpret_cast<const float4*>(&KT[kk * 4 + u][jbase]);
#pragma unroll
      for (int i = 0; i < 4; ++i) {
        s[i][0] += qv[i].x * ktv[0].x + qv[i].y * ktv[1].x + qv[i].z * ktv[2].x + qv[i].w * ktv[3].x;
        s[i][1] += qv[i].x * ktv[0].y + qv[i].y * ktv[1].y + qv[i].z * ktv[2].y + qv[i].w * ktv[3].y;
        s[i][2] += qv[i].x * ktv[0].z + qv[i].y * ktv[1].z + qv[i].z * ktv[2].z + qv[i].w * ktv[3].z;
        s[i][3] += qv[i].x * ktv[0].w + qv[i].y * ktv[1].w + qv[i].z * ktv[2].w + qv[i].w * ktv[3].w;
      }
    }

// online softmax update (rows live in 16-lane groups -> xor 1,2,4,8)
#pragma unroll
    for (int i = 0; i < 4; ++i) {
      s[i][0] *= SCALEv;
      s[i][1] *= SCALEv;
      s[i][2] *= SCALEv;
      s[i][3] *= SCALEv;
      float tmax = fmaxf(fmaxf(s[i][0], s[i][1]), fmaxf(s[i][2], s[i][3]));
      tmax = fmaxf(tmax, __shfl_xor(tmax, 1));
      tmax = fmaxf(tmax, __shfl_xor(tmax, 2));
      tmax = fmaxf(tmax, __shfl_xor(tmax, 4));
      tmax = fmaxf(tmax, __shfl_xor(tmax, 8));
      const float mnew = fmaxf(mrow[i], tmax);
      const float p0 = __expf(s[i][0] - mnew);
      const float p1 = __expf(s[i][1] - mnew);
      const float p2 = __expf(s[i][2] - mnew);
      const float p3 = __expf(s[i][3] - mnew);
      float ts = p0 + p1 + p2 + p3;
      ts += __shfl_xor(ts, 1);
      ts += __shfl_xor(ts, 2);
      ts += __shfl_xor(ts, 4);
      ts += __shfl_xor(ts, 8);
      const float cf = __expf(mrow[i] - mnew);
      lrow[i] = lrow[i] * cf + ts;
      mrow[i] = mnew;
      acc[i][0] *= cf;
      acc[i][1] *= cf;
      acc[i][2] *= cf;
      acc[i][3] *= cf;
      *reinterpret_cast<float4*>(&Ps[rbase + i][jbase]) = make_float4(p0, p1, p2, p3);
    }
    __syncthreads(); // Ps visible

// acc += P V  (4 rows x 4 out-cols per thread)
#pragma unroll
    for (int jc = 0; jc < 16; ++jc) {
      float4 pv[4], vv[4];
#pragma unroll
      for (int i = 0; i < 4; ++i)
        pv[i] = *reinterpret_cast<const float4*>(&Ps[rbase + i][jc * 4]);
#pragma unroll
      for (int j = 0; j < 4; ++j)
        vv[j] = *reinterpret_cast<const float4*>(&Vs[jc * 4 + j][jbase]);
#pragma unroll
      for (int i = 0; i < 4; ++i) {
        acc[i][0] += pv[i].x * vv[0].x + pv[i].y * vv[1].x + pv[i].z * vv[2].x + pv[i].w * vv[3].x;
        acc[i][1] += pv[i].x * vv[0].y + pv[i].y * vv[1].y + pv[i].z * vv[2].y + pv[i].w * vv[3].y;
        acc[i][2] += pv[i].x * vv[0].z + pv[i].y * vv[1].z + pv[i].z * vv[2].z + pv[i].w * vv[3].z;
        acc[i][3] += pv[i].x * vv[0].w + pv[i].y * vv[1].w + pv[i].z * vv[2].w + pv[i].w * vv[3].w;
      }
    }
  }

// normalize and write z in (b, l, c) layout
#pragma unroll
  for (int i = 0; i < 4; ++i) {
    const float inv = 1.0f / lrow[i];
    float4 o = make_float4(acc[i][0] * inv, acc[i][1] * inv, acc[i][2] * inv, acc[i][3] * inv);
    *reinterpret_cast<float4*>(z + (size_t)(b * Lv + q0 + rbase + i) * Cv + h * CHv + jbase) = o;
  }
}

extern "C" void kernel_launch(void* const* d_in, const int* in_sizes, int n_in,
                              void* d_out, int out_size, void* d_ws, size_t ws_size,
                              hipStream_t stream) {
  const float* x = (const float*)d_in[0];
  const float* gamma = (const float*)d_in[1];
  const float* beta = (const float*)d_in[2];
  const float* w_xyz = (const float*)d_in[3];
  const float* b_xyz = (const float*)d_in[4];
  const float* w_end = (const float*)d_in[5];
  const float* b_end = (const float*)d_in[6];
  float* out = (float*)d_out;

  // workspace: [xn | qkv]; xn buffer is reused for attention output z
  float* xn = (float*)d_ws;                  // Mv*Cv floats = 16 MB
  float* qkvb = xn + (size_t)Mv * Cv;        // Mv*N3 floats = 48 MB

  ln_kernel<<<Mv / 4, 256, 0, stream>>>(x, gamma, beta, xn);
  gemm128<false><<<dim3(N3 / 128, Mv / 128), 256, 0, stream>>>(
      xn, w_xyz, b_xyz, nullptr, qkvb, Mv, N3, Cv);
  attn_kernel<<<dim3(Lv / 64, Hv, Bv), 256, 0, stream>>>(qkvb, xn); // z -> xn
  gemm128<true><<<dim3(Cv / 128, Mv / 128), 256, 0, stream>>>(
      xn, w_end, b_end, x, out, Mv, Cv, Cv);
}

// Round 4
// 451.486 us; speedup vs baseline: 3.0768x; 3.0768x over previous
//
#include <hip/hip_runtime.h>
#include <hip/hip_bf16.h>
#include <math.h>

// Problem constants
constexpr int Bv = 4, Lv = 2048, Cv = 512, Hv = 8, CHv = 64;
constexpr int Mv = Bv * Lv;      // 8192 rows
constexpr int N3 = 3 * Cv;       // 1536
constexpr float EPSv = 1e-5f;
constexpr float SCALEv = 0.125f; // 1/sqrt(64)
constexpr int LDST = 76;         // LDS row stride (elem): 38 dwords ≡ 6 mod 32 → ≤2-way banks

typedef __attribute__((ext_vector_type(4))) float f32x4;
typedef __attribute__((ext_vector_type(8))) short bf16x8; // 8 bf16 in 4 VGPRs

__device__ inline unsigned short f2bf(float f) { // RNE float->bf16
  unsigned int u = __float_as_uint(f);
  unsigned int r = (u + 0x7fffu + ((u >> 16) & 1u)) >> 16;
  return (unsigned short)r;
}

// ---------------- LayerNorm: one wave per 512-float row ----------------
__global__ __launch_bounds__(256) void ln_kernel(const float* __restrict__ x,
                                                 const float* __restrict__ gamma,
                                                 const float* __restrict__ beta,
                                                 float* __restrict__ xn) {
  const int row = blockIdx.x * 4 + (threadIdx.x >> 6);
  const int lane = threadIdx.x & 63;
  const float4* xr = reinterpret_cast<const float4*>(x + (size_t)row * Cv);
  float4 v0 = xr[lane];
  float4 v1 = xr[lane + 64];
  float s = v0.x + v0.y + v0.z + v0.w + v1.x + v1.y + v1.z + v1.w;
  float q = v0.x * v0.x + v0.y * v0.y + v0.z * v0.z + v0.w * v0.w +
            v1.x * v1.x + v1.y * v1.y + v1.z * v1.z + v1.w * v1.w;
#pragma unroll
  for (int m = 1; m < 64; m <<= 1) {
    s += __shfl_xor(s, m, 64);
    q += __shfl_xor(q, m, 64);
  }
  const float mu = s * (1.0f / Cv);
  const float var = q * (1.0f / Cv) - mu * mu;
  const float rstd = rsqrtf(var + EPSv);
  const float4* g4 = reinterpret_cast<const float4*>(gamma);
  const float4* b4 = reinterpret_cast<const float4*>(beta);
  float4 ga = g4[lane], gb = g4[lane + 64];
  float4 ba = b4[lane], bb = b4[lane + 64];
  float4 o0, o1;
  o0.x = (v0.x - mu) * rstd * ga.x + ba.x;
  o0.y = (v0.y - mu) * rstd * ga.y + ba.y;
  o0.z = (v0.z - mu) * rstd * ga.z + ba.z;
  o0.w = (v0.w - mu) * rstd * ga.w + ba.w;
  o1.x = (v1.x - mu) * rstd * gb.x + bb.x;
  o1.y = (v1.y - mu) * rstd * gb.y + bb.y;
  o1.z = (v1.z - mu) * rstd * gb.z + bb.z;
  o1.w = (v1.w - mu) * rstd * gb.w + bb.w;
  float4* xo = reinterpret_cast<float4*>(xn + (size_t)row * Cv);
  xo[lane] = o0;
  xo[lane + 64] = o1;
}

// ---------------- fp32 GEMM: C = A(MxK)*B(KxN) + bias (+res); out fp32 or bf16
template <bool RES, bool OUTBF>
__global__ __launch_bounds__(256) void gemm128(const float* __restrict__ A,
                                               const float* __restrict__ Bm,
                                               const float* __restrict__ bias,
                                               const float* __restrict__ res,
                                               float* __restrict__ Cf,
                                               unsigned short* __restrict__ Cb,
                                               int M, int N, int K) {
  __shared__ float As[16][132];
  __shared__ float Bs[16][132];
  const int t = threadIdx.x;
  const int m0 = blockIdx.y * 128;
  const int n0 = blockIdx.x * 128;
  const int rg = t >> 4;
  const int cg = t & 15;
  const int ar = t >> 2;
  const int af = t & 3;
  const int br = t >> 5;
  const int bf = t & 31;

  float acc[8][8];
#pragma unroll
  for (int i = 0; i < 8; ++i)
#pragma unroll
    for (int j = 0; j < 8; ++j) acc[i][j] = 0.0f;

  for (int k0 = 0; k0 < K; k0 += 16) {
    float4 a0 = *reinterpret_cast<const float4*>(A + (size_t)(m0 + ar) * K + k0 + af * 4);
    float4 a1 = *reinterpret_cast<const float4*>(A + (size_t)(m0 + ar + 64) * K + k0 + af * 4);
    float4 b0 = *reinterpret_cast<const float4*>(Bm + (size_t)(k0 + br) * N + n0 + bf * 4);
    float4 b1 = *reinterpret_cast<const float4*>(Bm + (size_t)(k0 + br + 8) * N + n0 + bf * 4);
    __syncthreads();
    As[af * 4 + 0][ar] = a0.x;
    As[af * 4 + 1][ar] = a0.y;
    As[af * 4 + 2][ar] = a0.z;
    As[af * 4 + 3][ar] = a0.w;
    As[af * 4 + 0][ar + 64] = a1.x;
    As[af * 4 + 1][ar + 64] = a1.y;
    As[af * 4 + 2][ar + 64] = a1.z;
    As[af * 4 + 3][ar + 64] = a1.w;
    *reinterpret_cast<float4*>(&Bs[br][bf * 4]) = b0;
    *reinterpret_cast<float4*>(&Bs[br + 8][bf * 4]) = b1;
    __syncthreads();
#pragma unroll
    for (int kk = 0; kk < 16; ++kk) {
      float4 aA = *reinterpret_cast<const float4*>(&As[kk][rg * 4]);
      float4 aB = *reinterpret_cast<const float4*>(&As[kk][64 + rg * 4]);
      float4 bA = *reinterpret_cast<const float4*>(&Bs[kk][cg * 4]);
      float4 bB = *reinterpret_cast<const float4*>(&Bs[kk][64 + cg * 4]);
      float a[8] = {aA.x, aA.y, aA.z, aA.w, aB.x, aB.y, aB.z, aB.w};
      float bb_[8] = {bA.x, bA.y, bA.z, bA.w, bB.x, bB.y, bB.z, bB.w};
#pragma unroll
      for (int i = 0; i < 8; ++i)
#pragma unroll
        for (int j = 0; j < 8; ++j) acc[i][j] += a[i] * bb_[j];
    }
  }

#pragma unroll
  for (int i = 0; i < 8; ++i) {
    const int row = m0 + rg * 4 + (i & 3) + (i >> 2) * 64;
#pragma unroll
    for (int jh = 0; jh < 2; ++jh) {
      const int col = n0 + cg * 4 + jh * 64;
      float4 c;
      c.x = acc[i][jh * 4 + 0] + bias[col + 0];
      c.y = acc[i][jh * 4 + 1] + bias[col + 1];
      c.z = acc[i][jh * 4 + 2] + bias[col + 2];
      c.w = acc[i][jh * 4 + 3] + bias[col + 3];
      if (RES) {
        float4 r = *reinterpret_cast<const float4*>(res + (size_t)row * N + col);
        c.x += r.x;
        c.y += r.y;
        c.z += r.z;
        c.w += r.w;
      }
      if (OUTBF) {
        ushort4 u;
        u.x = f2bf(c.x);
        u.y = f2bf(c.y);
        u.z = f2bf(c.z);
        u.w = f2bf(c.w);
        *reinterpret_cast<ushort4*>(Cb + (size_t)row * N + col) = u;
      } else {
        *reinterpret_cast<float4*>(Cf + (size_t)row * N + col) = c;
      }
    }
  }
}

// ---------------- bf16 MFMA flash attention ----------------
// Block: one (b,h), 64 q-rows; 4 waves x 16 rows. K-tiles of 64 keys.
// mfma_f32_16x16x32_bf16 layouts: A/B lane l: 8 contig k at (l>>4)*8, row/col l&15;
// D: col=l&15, row=(l>>4)*4+r (m89-verified).
__global__ __launch_bounds__(256) void attn_mfma(const unsigned short* __restrict__ qkv,
                                                 float* __restrict__ z) {
  __shared__ unsigned short Ks[64 * LDST]; // [key][ch]
  __shared__ unsigned short Vt[64 * LDST]; // [ch][key], key-dim XOR-swizzled by (ch>>3)<<3
  __shared__ unsigned short Ps[64 * LDST]; // [qrow][key], per-wave 16-row slice

  const int t = threadIdx.x;
  const int l = t & 63, w = t >> 6;
  const int lm = l & 15, lq = l >> 4;

  // XCD-aware swizzle: 128 consecutive remapped ids (4 full (b,h) groups) per XCD
  const int f = blockIdx.x + 32 * blockIdx.y + 256 * blockIdx.z;
  const int n = (f & 7) * 128 + (f >> 3);
  const int qt = n & 31, h = (n >> 5) & 7, b = n >> 8;
  const int q0 = qt * 64;

  const unsigned short* base = qkv + (size_t)b * Lv * N3;
  const int qcol = h * CHv, kcol = Cv + h * CHv, vcol = 2 * Cv + h * CHv;

  // Q A-fragments, loaded once straight from global
  bf16x8 qf0, qf1;
  {
    const unsigned short* qp = base + (size_t)(q0 + w * 16 + lm) * N3 + qcol + lq * 8;
    qf0 = *reinterpret_cast<const bf16x8*>(qp);
    qf1 = *reinterpret_cast<const bf16x8*>(qp + 32);
  }

  // staging map: thread t handles rows sr, sr+32; 16B ch-chunk sc
  const int sr = t >> 3, sc = t & 7;

  // prefetch tile 0
  bf16x8 kr0, kr1, vr0, vr1;
  {
    const unsigned short* kp = base + (size_t)sr * N3 + kcol + sc * 8;
    const unsigned short* vp = base + (size_t)sr * N3 + vcol + sc * 8;
    kr0 = *reinterpret_cast<const bf16x8*>(kp);
    kr1 = *reinterpret_cast<const bf16x8*>(kp + (size_t)32 * N3);
    vr0 = *reinterpret_cast<const bf16x8*>(vp);
    vr1 = *reinterpret_cast<const bf16x8*>(vp + (size_t)32 * N3);
  }

  f32x4 accO[4];
#pragma unroll
  for (int i = 0; i < 4; ++i) accO[i] = f32x4{0.f, 0.f, 0.f, 0.f};
  float mrow[4] = {-INFINITY, -INFINITY, -INFINITY, -INFINITY};
  float lrow[4] = {0.f, 0.f, 0.f, 0.f};

  for (int kt = 0; kt < Lv / 64; ++kt) {
    __syncthreads(); // A: previous tile's LDS reads done (drains prev prefetch)
    // stage K (row-major) and V (transposed, swizzled) from regs
    *reinterpret_cast<bf16x8*>(&Ks[sr * LDST + sc * 8]) = kr0;
    *reinterpret_cast<bf16x8*>(&Ks[(sr + 32) * LDST + sc * 8]) = kr1;
    {
      const unsigned short* v0 = reinterpret_cast<const unsigned short*>(&vr0);
      const unsigned short* v1 = reinterpret_cast<const unsigned short*>(&vr1);
#pragma unroll
      for (int j = 0; j < 8; ++j) {
        Vt[(sc * 8 + j) * LDST + (sr ^ (sc << 3))] = v0[j];
        Vt[(sc * 8 + j) * LDST + ((sr + 32) ^ (sc << 3))] = v1[j];
      }
    }
    __syncthreads(); // B: tile visible

    // T14 async-STAGE: issue next tile's loads AFTER barrier B so the implicit
    // vmcnt(0) drain at barrier B doesn't serialize them; they stay in flight
    // across the whole compute phase and drain at next iteration's barrier A.
    if (kt + 1 < Lv / 64) {
      const unsigned short* kp = base + (size_t)((kt + 1) * 64 + sr) * N3 + kcol + sc * 8;
      const unsigned short* vp = base + (size_t)((kt + 1) * 64 + sr) * N3 + vcol + sc * 8;
      kr0 = *reinterpret_cast<const bf16x8*>(kp);
      kr1 = *reinterpret_cast<const bf16x8*>(kp + (size_t)32 * N3);
      vr0 = *reinterpret_cast<const bf16x8*>(vp);
      vr1 = *reinterpret_cast<const bf16x8*>(vp + (size_t)32 * N3);
    }

    // ---- S = Q K^T : 4 key-subtiles x 2 k-steps ----
    f32x4 sacc[4];
#pragma unroll
    for (int s = 0; s < 4; ++s) {
      bf16x8 kf0 = *reinterpret_cast<const bf16x8*>(&Ks[(16 * s + lm) * LDST + lq * 8]);
      bf16x8 kf1 = *reinterpret_cast<const bf16x8*>(&Ks[(16 * s + lm) * LDST + lq * 8 + 32]);
      f32x4 zz = f32x4{0.f, 0.f, 0.f, 0.f};
      sacc[s] = __builtin_amdgcn_mfma_f32_16x16x32_bf16(qf0, kf0, zz, 0, 0, 0);
      sacc[s] = __builtin_amdgcn_mfma_f32_16x16x32_bf16(qf1, kf1, sacc[s], 0, 0, 0);
    }

    // ---- online softmax on D-layout (row in one 16-lane group) ----
#pragma unroll
    for (int r = 0; r < 4; ++r) {
      float s0 = sacc[0][r] * SCALEv, s1 = sacc[1][r] * SCALEv;
      float s2 = sacc[2][r] * SCALEv, s3 = sacc[3][r] * SCALEv;
      float tmax = fmaxf(fmaxf(s0, s1), fmaxf(s2, s3));
      tmax = fmaxf(tmax, __shfl_xor(tmax, 1));
      tmax = fmaxf(tmax, __shfl_xor(tmax, 2));
      tmax = fmaxf(tmax, __shfl_xor(tmax, 4));
      tmax = fmaxf(tmax, __shfl_xor(tmax, 8));
      const float mnew = fmaxf(mrow[r], tmax);
      const float p0 = __expf(s0 - mnew);
      const float p1 = __expf(s1 - mnew);
      const float p2 = __expf(s2 - mnew);
      const float p3 = __expf(s3 - mnew);
      float ts = p0 + p1 + p2 + p3;
      ts += __shfl_xor(ts, 1);
      ts += __shfl_xor(ts, 2);
      ts += __shfl_xor(ts, 4);
      ts += __shfl_xor(ts, 8);
      const float cf = __expf(mrow[r] - mnew);
      lrow[r] = lrow[r] * cf + ts;
      mrow[r] = mnew;
      accO[0][r] *= cf;
      accO[1][r] *= cf;
      accO[2][r] *= cf;
      accO[3][r] *= cf;
      const int prow = w * 16 + lq * 4 + r;
      Ps[prow * LDST + lm + 0] = f2bf(p0);
      Ps[prow * LDST + lm + 16] = f2bf(p1);
      Ps[prow * LDST + lm + 32] = f2bf(p2);
      Ps[prow * LDST + lm + 48] = f2bf(p3);
    }
    // same-wave Ps write->read (wave w only touches rows w*16..w*16+15): in-order DS

    // ---- O += P V : 2 k-steps x 4 ch-subtiles ----
#pragma unroll
    for (int ks = 0; ks < 2; ++ks) {
      bf16x8 pf = *reinterpret_cast<const bf16x8*>(&Ps[(w * 16 + lm) * LDST + ks * 32 + lq * 8]);
#pragma unroll
      for (int ot = 0; ot < 4; ++ot) {
        const int ch = 16 * ot + lm;
        const int x = ch >> 3;
        bf16x8 vf = *reinterpret_cast<const bf16x8*>(&Vt[ch * LDST + (((4 * ks + lq) ^ x) << 3)]);
        accO[ot] = __builtin_amdgcn_mfma_f32_16x16x32_bf16(pf, vf, accO[ot], 0, 0, 0);
      }
    }
  }

  // normalize and write z (fp32, (b,l,c) layout)
#pragma unroll
  for (int r = 0; r < 4; ++r) {
    const float inv = 1.0f / lrow[r];
    const size_t row = (size_t)(b * Lv + q0 + w * 16 + lq * 4 + r);
#pragma unroll
    for (int ot = 0; ot < 4; ++ot)
      z[row * Cv + h * CHv + 16 * ot + lm] = accO[ot][r] * inv;
  }
}

extern "C" void kernel_launch(void* const* d_in, const int* in_sizes, int n_in,
                              void* d_out, int out_size, void* d_ws, size_t ws_size,
                              hipStream_t stream) {
  const float* x = (const float*)d_in[0];
  const float* gamma = (const float*)d_in[1];
  const float* beta = (const float*)d_in[2];
  const float* w_xyz = (const float*)d_in[3];
  const float* b_xyz = (const float*)d_in[4];
  const float* w_end = (const float*)d_in[5];
  const float* b_end = (const float*)d_in[6];
  float* out = (float*)d_out;

  float* xn = (float*)d_ws;                                 // 16 MB fp32 (reused for z)
  unsigned short* qkvb = (unsigned short*)(xn + (size_t)Mv * Cv); // 24 MB bf16

  ln_kernel<<<Mv / 4, 256, 0, stream>>>(x, gamma, beta, xn);
  gemm128<false, true><<<dim3(N3 / 128, Mv / 128), 256, 0, stream>>>(
      xn, w_xyz, b_xyz, nullptr, nullptr, qkvb, Mv, N3, Cv);
  attn_mfma<<<dim3(Lv / 64, Hv, Bv), 256, 0, stream>>>(qkvb, xn); // z -> xn
  gemm128<true, false><<<dim3(Cv / 128, Mv / 128), 256, 0, stream>>>(
      xn, w_end, b_end, x, out, nullptr, Mv, Cv, Cv);
}

// Round 6
// 276.555 us; speedup vs baseline: 5.0230x; 1.6325x over previous
//
#include <hip/hip_runtime.h>
#include <hip/hip_bf16.h>
#include <math.h>

// Problem constants
constexpr int Bv = 4, Lv = 2048, Cv = 512, Hv = 8, CHv = 64;
constexpr int Mv = Bv * Lv;      // 8192 rows
constexpr int N3 = 3 * Cv;       // 1536
constexpr float EPSv = 1e-5f;
constexpr float SCALEv = 0.125f; // 1/sqrt(64)
constexpr int LDST = 76;         // attn LDS row stride (elem): 38 dw ≡ 6 mod 32 → ≤2-way banks

typedef __attribute__((ext_vector_type(4))) float f32x4;
typedef __attribute__((ext_vector_type(8))) short bf16x8; // 8 bf16 in 4 VGPRs

__device__ inline unsigned short f2bf(float f) { // RNE float->bf16
  unsigned int u = __float_as_uint(f);
  unsigned int r = (u + 0x7fffu + ((u >> 16) & 1u)) >> 16;
  return (unsigned short)r;
}

// async global->LDS, 16B per lane; LDS dest = wave-uniform base + lane*16 (HW rule)
__device__ __forceinline__ void async_copy16(void* lp, const void* gp) {
  __builtin_amdgcn_global_load_lds(
      (const __attribute__((address_space(1))) void*)gp,
      (__attribute__((address_space(3))) void*)lp, 16, 0, 0);
}

// ---------------- LayerNorm: one wave per 512-float row; bf16 out ----------
__global__ __launch_bounds__(256) void ln_kernel(const float* __restrict__ x,
                                                 const float* __restrict__ gamma,
                                                 const float* __restrict__ beta,
                                                 unsigned short* __restrict__ xnb) {
  const int row = blockIdx.x * 4 + (threadIdx.x >> 6);
  const int lane = threadIdx.x & 63;
  const float4* xr = reinterpret_cast<const float4*>(x + (size_t)row * Cv);
  float4 v0 = xr[lane];
  float4 v1 = xr[lane + 64];
  float s = v0.x + v0.y + v0.z + v0.w + v1.x + v1.y + v1.z + v1.w;
  float q = v0.x * v0.x + v0.y * v0.y + v0.z * v0.z + v0.w * v0.w +
            v1.x * v1.x + v1.y * v1.y + v1.z * v1.z + v1.w * v1.w;
#pragma unroll
  for (int m = 1; m < 64; m <<= 1) {
    s += __shfl_xor(s, m, 64);
    q += __shfl_xor(q, m, 64);
  }
  const float mu = s * (1.0f / Cv);
  const float var = q * (1.0f / Cv) - mu * mu;
  const float rstd = rsqrtf(var + EPSv);
  const float4* g4 = reinterpret_cast<const float4*>(gamma);
  const float4* b4 = reinterpret_cast<const float4*>(beta);
  float4 ga = g4[lane], gb = g4[lane + 64];
  float4 ba = b4[lane], bb = b4[lane + 64];
  ushort4 u0, u1;
  u0.x = f2bf((v0.x - mu) * rstd * ga.x + ba.x);
  u0.y = f2bf((v0.y - mu) * rstd * ga.y + ba.y);
  u0.z = f2bf((v0.z - mu) * rstd * ga.z + ba.z);
  u0.w = f2bf((v0.w - mu) * rstd * ga.w + ba.w);
  u1.x = f2bf((v1.x - mu) * rstd * gb.x + bb.x);
  u1.y = f2bf((v1.y - mu) * rstd * gb.y + bb.y);
  u1.z = f2bf((v1.z - mu) * rstd * gb.z + bb.z);
  u1.w = f2bf((v1.w - mu) * rstd * gb.w + bb.w);
  ushort4* xo = reinterpret_cast<ushort4*>(xnb + (size_t)row * Cv);
  xo[lane] = u0;
  xo[lane + 64] = u1;
}

// ------------- transpose + fp32->bf16: out[c][r] = in[r][c] ----------------
__global__ __launch_bounds__(256) void transpose_f2b(const float* __restrict__ in,
                                                     unsigned short* __restrict__ out,
                                                     int R, int Cn) {
  __shared__ float Tl[64][65];
  const int t = threadIdx.x;
  const int tr = t >> 6, tc = t & 63;
  const int r0 = blockIdx.y * 64, c0 = blockIdx.x * 64;
#pragma unroll
  for (int i = 0; i < 16; ++i)
    Tl[tr + i * 4][tc] = in[(size_t)(r0 + tr + i * 4) * Cn + c0 + tc];
  __syncthreads();
#pragma unroll
  for (int i = 0; i < 16; ++i)
    out[(size_t)(c0 + tr + i * 4) * R + r0 + tc] = f2bf(Tl[tc][tr + i * 4]);
}

// ---------------- bf16 MFMA GEMM: C = A(MxK) * Bt^T + bias (+res) ----------
// A bf16 [M][K] row-major, Bt bf16 [N][K] row-major (pre-transposed B).
// m97 structure: 128x128 tile, BK=64, global_load_lds w16, XOR chunk-swizzle
// (pre-swizzled global source, rule #21), b128 fragment reads, 2-barrier loop.
template <bool RES, bool OUTBF>
__global__ __launch_bounds__(256) void gemm_mfma(const unsigned short* __restrict__ A,
                                                 const unsigned short* __restrict__ Bt,
                                                 const float* __restrict__ bias,
                                                 const float* __restrict__ res,
                                                 float* __restrict__ Cf,
                                                 unsigned short* __restrict__ Cb,
                                                 int M, int N, int K) {
  __shared__ unsigned short Al[128 * 64]; // [row][64k], chunk-swizzled content
  __shared__ unsigned short Bl[128 * 64];
  const int t = threadIdx.x;
  const int l = t & 63, w = t >> 6;
  const int lm = l & 15, lq = l >> 4;
  const int m0 = blockIdx.y * 128, n0 = blockIdx.x * 128;
  const int rw0 = (w >> 1) * 64, cw0 = (w & 1) * 64; // wave's 64x64 sub-tile

  f32x4 acc[4][4];
#pragma unroll
  for (int mi = 0; mi < 4; ++mi)
#pragma unroll
    for (int ni = 0; ni < 4; ++ni) acc[mi][ni] = f32x4{0.f, 0.f, 0.f, 0.f};

  const int sr8 = l >> 3; // staging: lane's row-within-8
  const int sc = l & 7;   // lane's linear 16B chunk

  for (int k0 = 0; k0 < K; k0 += 64) {
    // stage: wave w covers rows w*32 .. w*32+31 of both tiles (4 instr each)
#pragma unroll
    for (int j = 0; j < 4; ++j) {
      const int row = w * 32 + j * 8 + sr8;
      const int cs = sc ^ (row & 7); // pre-swizzled global chunk
      async_copy16(&Al[(w * 32 + j * 8) * 64],
                   A + (size_t)(m0 + row) * K + k0 + cs * 8);
      async_copy16(&Bl[(w * 32 + j * 8) * 64],
                   Bt + (size_t)(n0 + row) * K + k0 + cs * 8);
    }
    __syncthreads(); // vmcnt(0) drain -> tile visible

    bf16x8 af[4][2], bfr[4][2];
#pragma unroll
    for (int mi = 0; mi < 4; ++mi) {
      const int r = rw0 + mi * 16 + lm;
#pragma unroll
      for (int ks = 0; ks < 2; ++ks) {
        const int c = (ks * 4 + lq) ^ (r & 7); // swizzled read
        af[mi][ks] = *reinterpret_cast<const bf16x8*>(&Al[r * 64 + c * 8]);
      }
    }
#pragma unroll
    for (int ni = 0; ni < 4; ++ni) {
      const int r = cw0 + ni * 16 + lm;
#pragma unroll
      for (int ks = 0; ks < 2; ++ks) {
        const int c = (ks * 4 + lq) ^ (r & 7);
        bfr[ni][ks] = *reinterpret_cast<const bf16x8*>(&Bl[r * 64 + c * 8]);
      }
    }
#pragma unroll
    for (int ks = 0; ks < 2; ++ks)
#pragma unroll
      for (int mi = 0; mi < 4; ++mi)
#pragma unroll
        for (int ni = 0; ni < 4; ++ni)
          acc[mi][ni] = __builtin_amdgcn_mfma_f32_16x16x32_bf16(
              af[mi][ks], bfr[ni][ks], acc[mi][ni], 0, 0, 0);
    __syncthreads(); // reads done before next overwrite
  }

  // epilogue: D layout col=l&15, row=(l>>4)*4+r (HW-validated by attn kernel)
#pragma unroll
  for (int mi = 0; mi < 4; ++mi)
#pragma unroll
    for (int ni = 0; ni < 4; ++ni) {
      const int col = n0 + cw0 + ni * 16 + lm;
      const float bv = bias[col];
#pragma unroll
      for (int r = 0; r < 4; ++r) {
        const int row = m0 + rw0 + mi * 16 + lq * 4 + r;
        float v = acc[mi][ni][r] + bv;
        if (RES) v += res[(size_t)row * N + col];
        if (OUTBF)
          Cb[(size_t)row * N + col] = f2bf(v);
        else
          Cf[(size_t)row * N + col] = v;
      }
    }
}

// ---------------- bf16 MFMA flash attention (HW-verified in R4) ------------
__global__ __launch_bounds__(256) void attn_mfma(const unsigned short* __restrict__ qkv,
                                                 unsigned short* __restrict__ zb) {
  __shared__ unsigned short Ks[64 * LDST]; // [key][ch]
  __shared__ unsigned short Vt[64 * LDST]; // [ch][key], key-dim XOR-swizzled
  __shared__ unsigned short Ps[64 * LDST]; // [qrow][key]

  const int t = threadIdx.x;
  const int l = t & 63, w = t >> 6;
  const int lm = l & 15, lq = l >> 4;

  const int f = blockIdx.x + 32 * blockIdx.y + 256 * blockIdx.z;
  const int n = (f & 7) * 128 + (f >> 3); // XCD swizzle (1024 % 8 == 0)
  const int qt = n & 31, h = (n >> 5) & 7, b = n >> 8;
  const int q0 = qt * 64;

  const unsigned short* base = qkv + (size_t)b * Lv * N3;
  const int kcol = Cv + h * CHv, vcol = 2 * Cv + h * CHv;

  bf16x8 qf0, qf1;
  {
    const unsigned short* qp = base + (size_t)(q0 + w * 16 + lm) * N3 + h * CHv + lq * 8;
    qf0 = *reinterpret_cast<const bf16x8*>(qp);
    qf1 = *reinterpret_cast<const bf16x8*>(qp + 32);
  }

  const int sr = t >> 3, sc = t & 7;

  bf16x8 kr0, kr1, vr0, vr1;
  {
    const unsigned short* kp = base + (size_t)sr * N3 + kcol + sc * 8;
    const unsigned short* vp = base + (size_t)sr * N3 + vcol + sc * 8;
    kr0 = *reinterpret_cast<const bf16x8*>(kp);
    kr1 = *reinterpret_cast<const bf16x8*>(kp + (size_t)32 * N3);
    vr0 = *reinterpret_cast<const bf16x8*>(vp);
    vr1 = *reinterpret_cast<const bf16x8*>(vp + (size_t)32 * N3);
  }

  f32x4 accO[4];
#pragma unroll
  for (int i = 0; i < 4; ++i) accO[i] = f32x4{0.f, 0.f, 0.f, 0.f};
  float mrow[4] = {-INFINITY, -INFINITY, -INFINITY, -INFINITY};
  float lrow[4] = {0.f, 0.f, 0.f, 0.f};

  for (int kt = 0; kt < Lv / 64; ++kt) {
    __syncthreads(); // A: previous tile's LDS reads done
    *reinterpret_cast<bf16x8*>(&Ks[sr * LDST + sc * 8]) = kr0;
    *reinterpret_cast<bf16x8*>(&Ks[(sr + 32) * LDST + sc * 8]) = kr1;
    {
      const unsigned short* v0 = reinterpret_cast<const unsigned short*>(&vr0);
      const unsigned short* v1 = reinterpret_cast<const unsigned short*>(&vr1);
#pragma unroll
      for (int j = 0; j < 8; ++j) {
        Vt[(sc * 8 + j) * LDST + (sr ^ (sc << 3))] = v0[j];
        Vt[(sc * 8 + j) * LDST + ((sr + 32) ^ (sc << 3))] = v1[j];
      }
    }
    __syncthreads(); // B: tile visible

    // T14: issue next tile's loads after barrier B; drain at next iter's A
    if (kt + 1 < Lv / 64) {
      const unsigned short* kp = base + (size_t)((kt + 1) * 64 + sr) * N3 + kcol + sc * 8;
      const unsigned short* vp = base + (size_t)((kt + 1) * 64 + sr) * N3 + vcol + sc * 8;
      kr0 = *reinterpret_cast<const bf16x8*>(kp);
      kr1 = *reinterpret_cast<const bf16x8*>(kp + (size_t)32 * N3);
      vr0 = *reinterpret_cast<const bf16x8*>(vp);
      vr1 = *reinterpret_cast<const bf16x8*>(vp + (size_t)32 * N3);
    }

    f32x4 sacc[4];
#pragma unroll
    for (int s = 0; s < 4; ++s) {
      bf16x8 kf0 = *reinterpret_cast<const bf16x8*>(&Ks[(16 * s + lm) * LDST + lq * 8]);
      bf16x8 kf1 = *reinterpret_cast<const bf16x8*>(&Ks[(16 * s + lm) * LDST + lq * 8 + 32]);
      f32x4 zz = f32x4{0.f, 0.f, 0.f, 0.f};
      sacc[s] = __builtin_amdgcn_mfma_f32_16x16x32_bf16(qf0, kf0, zz, 0, 0, 0);
      sacc[s] = __builtin_amdgcn_mfma_f32_16x16x32_bf16(qf1, kf1, sacc[s], 0, 0, 0);
    }

#pragma unroll
    for (int r = 0; r < 4; ++r) {
      float s0 = sacc[0][r] * SCALEv, s1 = sacc[1][r] * SCALEv;
      float s2 = sacc[2][r] * SCALEv, s3 = sacc[3][r] * SCALEv;
      float tmax = fmaxf(fmaxf(s0, s1), fmaxf(s2, s3));
      tmax = fmaxf(tmax, __shfl_xor(tmax, 1));
      tmax = fmaxf(tmax, __shfl_xor(tmax, 2));
      tmax = fmaxf(tmax, __shfl_xor(tmax, 4));
      tmax = fmaxf(tmax, __shfl_xor(tmax, 8));
      const float mnew = fmaxf(mrow[r], tmax);
      const float p0 = __expf(s0 - mnew);
      const float p1 = __expf(s1 - mnew);
      const float p2 = __expf(s2 - mnew);
      const float p3 = __expf(s3 - mnew);
      float ts = p0 + p1 + p2 + p3;
      ts += __shfl_xor(ts, 1);
      ts += __shfl_xor(ts, 2);
      ts += __shfl_xor(ts, 4);
      ts += __shfl_xor(ts, 8);
      const float cf = __expf(mrow[r] - mnew);
      lrow[r] = lrow[r] * cf + ts;
      mrow[r] = mnew;
      accO[0][r] *= cf;
      accO[1][r] *= cf;
      accO[2][r] *= cf;
      accO[3][r] *= cf;
      const int prow = w * 16 + lq * 4 + r;
      Ps[prow * LDST + lm + 0] = f2bf(p0);
      Ps[prow * LDST + lm + 16] = f2bf(p1);
      Ps[prow * LDST + lm + 32] = f2bf(p2);
      Ps[prow * LDST + lm + 48] = f2bf(p3);
    }

#pragma unroll
    for (int ks = 0; ks < 2; ++ks) {
      bf16x8 pf = *reinterpret_cast<const bf16x8*>(&Ps[(w * 16 + lm) * LDST + ks * 32 + lq * 8]);
#pragma unroll
      for (int ot = 0; ot < 4; ++ot) {
        const int ch = 16 * ot + lm;
        const int x = ch >> 3;
        bf16x8 vf = *reinterpret_cast<const bf16x8*>(&Vt[ch * LDST + (((4 * ks + lq) ^ x) << 3)]);
        accO[ot] = __builtin_amdgcn_mfma_f32_16x16x32_bf16(pf, vf, accO[ot], 0, 0, 0);
      }
    }
  }

#pragma unroll
  for (int r = 0; r < 4; ++r) {
    const float inv = 1.0f / lrow[r];
    const size_t row = (size_t)(b * Lv + q0 + w * 16 + lq * 4 + r);
#pragma unroll
    for (int ot = 0; ot < 4; ++ot)
      zb[row * Cv + h * CHv + 16 * ot + lm] = f2bf(accO[ot][r] * inv);
  }
}

extern "C" void kernel_launch(void* const* d_in, const int* in_sizes, int n_in,
                              void* d_out, int out_size, void* d_ws, size_t ws_size,
                              hipStream_t stream) {
  const float* x = (const float*)d_in[0];
  const float* gamma = (const float*)d_in[1];
  const float* beta = (const float*)d_in[2];
  const float* w_xyz = (const float*)d_in[3];
  const float* b_xyz = (const float*)d_in[4];
  const float* w_end = (const float*)d_in[5];
  const float* b_end = (const float*)d_in[6];
  float* out = (float*)d_out;

  // workspace (bf16 buffers)
  unsigned short* xnb = (unsigned short*)d_ws;            //  8 MB  [8192][512]
  unsigned short* qkvb = xnb + (size_t)Mv * Cv;           // 24 MB  [8192][1536]
  unsigned short* zb = qkvb + (size_t)Mv * N3;            //  8 MB  [8192][512]
  unsigned short* wxT = zb + (size_t)Mv * Cv;             // 1.5 MB [1536][512]
  unsigned short* weT = wxT + (size_t)N3 * Cv;            // 0.5 MB [512][512]

  transpose_f2b<<<dim3(N3 / 64, Cv / 64), 256, 0, stream>>>(w_xyz, wxT, Cv, N3);
  transpose_f2b<<<dim3(Cv / 64, Cv / 64), 256, 0, stream>>>(w_end, weT, Cv, Cv);
  ln_kernel<<<Mv / 4, 256, 0, stream>>>(x, gamma, beta, xnb);
  gemm_mfma<false, true><<<dim3(N3 / 128, Mv / 128), 256, 0, stream>>>(
      xnb, wxT, b_xyz, nullptr, nullptr, qkvb, Mv, N3, Cv);
  attn_mfma<<<dim3(Lv / 64, Hv, Bv), 256, 0, stream>>>(qkvb, zb);
  gemm_mfma<true, false><<<dim3(Cv / 128, Mv / 128), 256, 0, stream>>>(
      zb, weT, b_end, x, out, nullptr, Mv, Cv, Cv);
}

// Round 7
// 224.982 us; speedup vs baseline: 6.1744x; 1.2292x over previous
//
#include <hip/hip_runtime.h>
#include <hip/hip_bf16.h>
#include <math.h>

// Problem constants
constexpr int Bv = 4, Lv = 2048, Cv = 512, Hv = 8, CHv = 64;
constexpr int Mv = Bv * Lv;      // 8192 rows
constexpr int N3 = 3 * Cv;       // 1536
constexpr float EPSv = 1e-5f;
constexpr float SCALEv = 0.125f;                 // 1/sqrt(64)
constexpr float K2v = 0.125f * 1.44269504089f;   // scale * log2(e), exp2-domain softmax
constexpr int LDST = 76; // K/V LDS row stride (elem): 38 dw ≡ 6 mod 32 → ≤2-way banks
constexpr int PSTR = 68; // Ps row stride

typedef __attribute__((ext_vector_type(4))) float f32x4;
typedef __attribute__((ext_vector_type(8))) short bf16x8; // 8 bf16 in 4 VGPRs

__device__ inline unsigned short f2bf(float f) { // RNE float->bf16
  unsigned int u = __float_as_uint(f);
  unsigned int r = (u + 0x7fffu + ((u >> 16) & 1u)) >> 16;
  return (unsigned short)r;
}

// async global->LDS, 16B per lane; LDS dest = wave-uniform base + lane*16 (HW rule)
__device__ __forceinline__ void async_copy16(void* lp, const void* gp) {
  __builtin_amdgcn_global_load_lds(
      (const __attribute__((address_space(1))) void*)gp,
      (__attribute__((address_space(3))) void*)lp, 16, 0, 0);
}

// ---------------- LayerNorm: one wave per 512-float row; bf16 out ----------
__global__ __launch_bounds__(256) void ln_kernel(const float* __restrict__ x,
                                                 const float* __restrict__ gamma,
                                                 const float* __restrict__ beta,
                                                 unsigned short* __restrict__ xnb) {
  const int row = blockIdx.x * 4 + (threadIdx.x >> 6);
  const int lane = threadIdx.x & 63;
  const float4* xr = reinterpret_cast<const float4*>(x + (size_t)row * Cv);
  float4 v0 = xr[lane];
  float4 v1 = xr[lane + 64];
  float s = v0.x + v0.y + v0.z + v0.w + v1.x + v1.y + v1.z + v1.w;
  float q = v0.x * v0.x + v0.y * v0.y + v0.z * v0.z + v0.w * v0.w +
            v1.x * v1.x + v1.y * v1.y + v1.z * v1.z + v1.w * v1.w;
#pragma unroll
  for (int m = 1; m < 64; m <<= 1) {
    s += __shfl_xor(s, m, 64);
    q += __shfl_xor(q, m, 64);
  }
  const float mu = s * (1.0f / Cv);
  const float var = q * (1.0f / Cv) - mu * mu;
  const float rstd = rsqrtf(var + EPSv);
  const float4* g4 = reinterpret_cast<const float4*>(gamma);
  const float4* b4 = reinterpret_cast<const float4*>(beta);
  float4 ga = g4[lane], gb = g4[lane + 64];
  float4 ba = b4[lane], bb = b4[lane + 64];
  ushort4 u0, u1;
  u0.x = f2bf((v0.x - mu) * rstd * ga.x + ba.x);
  u0.y = f2bf((v0.y - mu) * rstd * ga.y + ba.y);
  u0.z = f2bf((v0.z - mu) * rstd * ga.z + ba.z);
  u0.w = f2bf((v0.w - mu) * rstd * ga.w + ba.w);
  u1.x = f2bf((v1.x - mu) * rstd * gb.x + bb.x);
  u1.y = f2bf((v1.y - mu) * rstd * gb.y + bb.y);
  u1.z = f2bf((v1.z - mu) * rstd * gb.z + bb.z);
  u1.w = f2bf((v1.w - mu) * rstd * gb.w + bb.w);
  ushort4* xo = reinterpret_cast<ushort4*>(xnb + (size_t)row * Cv);
  xo[lane] = u0;
  xo[lane + 64] = u1;
}

// ------------- transpose + fp32->bf16: out[c][r] = in[r][c] ----------------
__global__ __launch_bounds__(256) void transpose_f2b(const float* __restrict__ in,
                                                     unsigned short* __restrict__ out,
                                                     int R, int Cn) {
  __shared__ float Tl[64][65];
  const int t = threadIdx.x;
  const int tr = t >> 6, tc = t & 63;
  const int r0 = blockIdx.y * 64, c0 = blockIdx.x * 64;
#pragma unroll
  for (int i = 0; i < 16; ++i)
    Tl[tr + i * 4][tc] = in[(size_t)(r0 + tr + i * 4) * Cn + c0 + tc];
  __syncthreads();
#pragma unroll
  for (int i = 0; i < 16; ++i)
    out[(size_t)(c0 + tr + i * 4) * R + r0 + tc] = f2bf(Tl[tc][tr + i * 4]);
}

// ---------------- bf16 MFMA GEMM: C = A(MxK) * Bt^T + bias (+res) ----------
// (HW-verified R6: m97 structure, 128x128 tile, BK=64, global_load_lds w16,
//  XOR chunk-swizzle with pre-swizzled global source, b128 fragment reads.)
template <bool RES, bool OUTBF>
__global__ __launch_bounds__(256) void gemm_mfma(const unsigned short* __restrict__ A,
                                                 const unsigned short* __restrict__ Bt,
                                                 const float* __restrict__ bias,
                                                 const float* __restrict__ res,
                                                 float* __restrict__ Cf,
                                                 unsigned short* __restrict__ Cb,
                                                 int M, int N, int K) {
  __shared__ unsigned short Al[128 * 64]; // [row][64k], chunk-swizzled content
  __shared__ unsigned short Bl[128 * 64];
  const int t = threadIdx.x;
  const int l = t & 63, w = t >> 6;
  const int lm = l & 15, lq = l >> 4;
  const int m0 = blockIdx.y * 128, n0 = blockIdx.x * 128;
  const int rw0 = (w >> 1) * 64, cw0 = (w & 1) * 64; // wave's 64x64 sub-tile

  f32x4 acc[4][4];
#pragma unroll
  for (int mi = 0; mi < 4; ++mi)
#pragma unroll
    for (int ni = 0; ni < 4; ++ni) acc[mi][ni] = f32x4{0.f, 0.f, 0.f, 0.f};

  const int sr8 = l >> 3; // staging: lane's row-within-8
  const int sc = l & 7;   // lane's linear 16B chunk

  for (int k0 = 0; k0 < K; k0 += 64) {
#pragma unroll
    for (int j = 0; j < 4; ++j) {
      const int row = w * 32 + j * 8 + sr8;
      const int cs = sc ^ (row & 7); // pre-swizzled global chunk
      async_copy16(&Al[(w * 32 + j * 8) * 64],
                   A + (size_t)(m0 + row) * K + k0 + cs * 8);
      async_copy16(&Bl[(w * 32 + j * 8) * 64],
                   Bt + (size_t)(n0 + row) * K + k0 + cs * 8);
    }
    __syncthreads(); // vmcnt(0) drain -> tile visible

    bf16x8 af[4][2], bfr[4][2];
#pragma unroll
    for (int mi = 0; mi < 4; ++mi) {
      const int r = rw0 + mi * 16 + lm;
#pragma unroll
      for (int ks = 0; ks < 2; ++ks) {
        const int c = (ks * 4 + lq) ^ (r & 7); // swizzled read
        af[mi][ks] = *reinterpret_cast<const bf16x8*>(&Al[r * 64 + c * 8]);
      }
    }
#pragma unroll
    for (int ni = 0; ni < 4; ++ni) {
      const int r = cw0 + ni * 16 + lm;
#pragma unroll
      for (int ks = 0; ks < 2; ++ks) {
        const int c = (ks * 4 + lq) ^ (r & 7);
        bfr[ni][ks] = *reinterpret_cast<const bf16x8*>(&Bl[r * 64 + c * 8]);
      }
    }
#pragma unroll
    for (int ks = 0; ks < 2; ++ks)
#pragma unroll
      for (int mi = 0; mi < 4; ++mi)
#pragma unroll
        for (int ni = 0; ni < 4; ++ni)
          acc[mi][ni] = __builtin_amdgcn_mfma_f32_16x16x32_bf16(
              af[mi][ks], bfr[ni][ks], acc[mi][ni], 0, 0, 0);
    __syncthreads(); // reads done before next overwrite
  }

#pragma unroll
  for (int mi = 0; mi < 4; ++mi)
#pragma unroll
    for (int ni = 0; ni < 4; ++ni) {
      const int col = n0 + cw0 + ni * 16 + lm;
      const float bv = bias[col];
#pragma unroll
      for (int r = 0; r < 4; ++r) {
        const int row = m0 + rw0 + mi * 16 + lq * 4 + r;
        float v = acc[mi][ni][r] + bv;
        if (RES) v += res[(size_t)row * N + col];
        if (OUTBF)
          Cb[(size_t)row * N + col] = f2bf(v);
        else
          Cf[(size_t)row * N + col] = v;
      }
    }
}

// ---------------- bf16 MFMA flash attention v2: swapped QK^T ---------------
// S^T = mfma(K, Q): free operand swap (A/B fragment lane maps identical).
// D of swapped QK: col=lm -> q, row=lq*4+r (+16s) -> key. Each lane owns ONE
// q-column (q = w*16+lm) with 16 of 64 keys in-register -> softmax reduce =
// in-lane tree + shfl_xor(16,32). P written as row-major Ps[q][key] with 4
// vectorized b64 writes (keys 16s+4lq+[0..3] are reg-consecutive), read back
// as standard b128 A-fragment for UNSWAPPED PV. cf/lsum are per-lane scalars.
__global__ __launch_bounds__(256) void attn_mfma(const unsigned short* __restrict__ qkv,
                                                 unsigned short* __restrict__ zb) {
  __shared__ unsigned short Ks[64 * LDST]; // [key][ch]
  __shared__ unsigned short Vt[64 * LDST]; // [ch][key], key-dim XOR-swizzled
  __shared__ unsigned short Ps[64 * PSTR]; // [qrow][key] row-major

  const int t = threadIdx.x;
  const int l = t & 63, w = t >> 6;
  const int lm = l & 15, lq = l >> 4;

  const int f = blockIdx.x + 32 * blockIdx.y + 256 * blockIdx.z;
  const int n = (f & 7) * 128 + (f >> 3); // XCD swizzle (1024 % 8 == 0)
  const int qt = n & 31, h = (n >> 5) & 7, b = n >> 8;
  const int q0 = qt * 64;

  const unsigned short* base = qkv + (size_t)b * Lv * N3;
  const int kcol = Cv + h * CHv, vcol = 2 * Cv + h * CHv;

  bf16x8 qf0, qf1; // Q fragment (used as B operand; same lane map as A role)
  {
    const unsigned short* qp = base + (size_t)(q0 + w * 16 + lm) * N3 + h * CHv + lq * 8;
    qf0 = *reinterpret_cast<const bf16x8*>(qp);
    qf1 = *reinterpret_cast<const bf16x8*>(qp + 32);
  }

  const int sr = t >> 3, sc = t & 7;

  bf16x8 kr0, kr1, vr0, vr1;
  {
    const unsigned short* kp = base + (size_t)sr * N3 + kcol + sc * 8;
    const unsigned short* vp = base + (size_t)sr * N3 + vcol + sc * 8;
    kr0 = *reinterpret_cast<const bf16x8*>(kp);
    kr1 = *reinterpret_cast<const bf16x8*>(kp + (size_t)32 * N3);
    vr0 = *reinterpret_cast<const bf16x8*>(vp);
    vr1 = *reinterpret_cast<const bf16x8*>(vp + (size_t)32 * N3);
  }

  f32x4 accO[4];
#pragma unroll
  for (int i = 0; i < 4; ++i) accO[i] = f32x4{0.f, 0.f, 0.f, 0.f};
  float m2 = -INFINITY; // running max, exp2 domain, for q = w*16+lm
  float lsum = 0.f;

  for (int kt = 0; kt < Lv / 64; ++kt) {
    __syncthreads(); // A: previous tile's LDS reads done
    *reinterpret_cast<bf16x8*>(&Ks[sr * LDST + sc * 8]) = kr0;
    *reinterpret_cast<bf16x8*>(&Ks[(sr + 32) * LDST + sc * 8]) = kr1;
    {
      const unsigned short* v0 = reinterpret_cast<const unsigned short*>(&vr0);
      const unsigned short* v1 = reinterpret_cast<const unsigned short*>(&vr1);
#pragma unroll
      for (int j = 0; j < 8; ++j) {
        Vt[(sc * 8 + j) * LDST + (sr ^ (sc << 3))] = v0[j];
        Vt[(sc * 8 + j) * LDST + ((sr + 32) ^ (sc << 3))] = v1[j];
      }
    }
    __syncthreads(); // B: tile visible

    // T14: issue next tile's loads after barrier B; drain at next iter's A
    if (kt + 1 < Lv / 64) {
      const unsigned short* kp = base + (size_t)((kt + 1) * 64 + sr) * N3 + kcol + sc * 8;
      const unsigned short* vp = base + (size_t)((kt + 1) * 64 + sr) * N3 + vcol + sc * 8;
      kr0 = *reinterpret_cast<const bf16x8*>(kp);
      kr1 = *reinterpret_cast<const bf16x8*>(kp + (size_t)32 * N3);
      vr0 = *reinterpret_cast<const bf16x8*>(vp);
      vr1 = *reinterpret_cast<const bf16x8*>(vp + (size_t)32 * N3);
    }

    // ---- S^T = K Q^T : 4 key-subtiles x 2 k-steps (swapped operands) ----
    f32x4 sacc[4];
#pragma unroll
    for (int s = 0; s < 4; ++s) {
      bf16x8 kf0 = *reinterpret_cast<const bf16x8*>(&Ks[(16 * s + lm) * LDST + lq * 8]);
      bf16x8 kf1 = *reinterpret_cast<const bf16x8*>(&Ks[(16 * s + lm) * LDST + lq * 8 + 32]);
      f32x4 zz = f32x4{0.f, 0.f, 0.f, 0.f};
      sacc[s] = __builtin_amdgcn_mfma_f32_16x16x32_bf16(kf0, qf0, zz, 0, 0, 0);
      sacc[s] = __builtin_amdgcn_mfma_f32_16x16x32_bf16(kf1, qf1, sacc[s], 0, 0, 0);
    }

    // ---- online softmax, exp2 domain; lane owns q = w*16+lm ----
    f32x4 m4 = __builtin_elementwise_max(__builtin_elementwise_max(sacc[0], sacc[1]),
                                         __builtin_elementwise_max(sacc[2], sacc[3]));
    float mx = fmaxf(fmaxf(m4[0], m4[1]), fmaxf(m4[2], m4[3]));
    mx = fmaxf(mx, __shfl_xor(mx, 16));
    mx = fmaxf(mx, __shfl_xor(mx, 32));
    const float m2new = fmaxf(m2, mx * K2v);

    f32x4 ps[4];
#pragma unroll
    for (int s = 0; s < 4; ++s)
#pragma unroll
      for (int r = 0; r < 4; ++r)
        ps[s][r] = exp2f(sacc[s][r] * K2v - m2new);

    // vectorized P write: keys 16s+4lq+[0..3] contiguous in Ps[q][key]
#pragma unroll
    for (int s = 0; s < 4; ++s) {
      uint2 pk;
      pk.x = (unsigned)f2bf(ps[s][0]) | ((unsigned)f2bf(ps[s][1]) << 16);
      pk.y = (unsigned)f2bf(ps[s][2]) | ((unsigned)f2bf(ps[s][3]) << 16);
      *reinterpret_cast<uint2*>(&Ps[(w * 16 + lm) * PSTR + 16 * s + 4 * lq]) = pk;
    }

    f32x4 s4 = (ps[0] + ps[1]) + (ps[2] + ps[3]);
    float psum = (s4[0] + s4[1]) + (s4[2] + s4[3]);
    psum += __shfl_xor(psum, 16);
    psum += __shfl_xor(psum, 32);

    const float cf = exp2f(m2 - m2new);
    lsum = lsum * cf + psum;
    m2 = m2new;
#pragma unroll
    for (int r = 0; r < 4; ++r) {
      const float cfr = __shfl(cf, lq * 4 + r); // cf for q = w*16+lq*4+r
      accO[0][r] *= cfr;
      accO[1][r] *= cfr;
      accO[2][r] *= cfr;
      accO[3][r] *= cfr;
    }
    // same-wave Ps write->read below: DS pipe in-order + compiler lgkmcnt

    // ---- O += P V (unswapped): A = Ps[q][key] b128, B = Vt b128 ----
#pragma unroll
    for (int ks = 0; ks < 2; ++ks) {
      bf16x8 pf = *reinterpret_cast<const bf16x8*>(&Ps[(w * 16 + lm) * PSTR + ks * 32 + lq * 8]);
#pragma unroll
      for (int ot = 0; ot < 4; ++ot) {
        const int ch = 16 * ot + lm;
        const int x = ch >> 3;
        bf16x8 vf = *reinterpret_cast<const bf16x8*>(&Vt[ch * LDST + (((4 * ks + lq) ^ x) << 3)]);
        accO[ot] = __builtin_amdgcn_mfma_f32_16x16x32_bf16(pf, vf, accO[ot], 0, 0, 0);
      }
    }
  }

  // normalize and write z; accO row r is q = w*16+lq*4+r, lsum lives at lane lm=q
#pragma unroll
  for (int r = 0; r < 4; ++r) {
    const float inv = 1.0f / __shfl(lsum, lq * 4 + r);
    const size_t row = (size_t)(b * Lv + q0 + w * 16 + lq * 4 + r);
#pragma unroll
    for (int ot = 0; ot < 4; ++ot)
      zb[row * Cv + h * CHv + 16 * ot + lm] = f2bf(accO[ot][r] * inv);
  }
}

extern "C" void kernel_launch(void* const* d_in, const int* in_sizes, int n_in,
                              void* d_out, int out_size, void* d_ws, size_t ws_size,
                              hipStream_t stream) {
  const float* x = (const float*)d_in[0];
  const float* gamma = (const float*)d_in[1];
  const float* beta = (const float*)d_in[2];
  const float* w_xyz = (const float*)d_in[3];
  const float* b_xyz = (const float*)d_in[4];
  const float* w_end = (const float*)d_in[5];
  const float* b_end = (const float*)d_in[6];
  float* out = (float*)d_out;

  // workspace (bf16 buffers)
  unsigned short* xnb = (unsigned short*)d_ws;            //  8 MB  [8192][512]
  unsigned short* qkvb = xnb + (size_t)Mv * Cv;           // 24 MB  [8192][1536]
  unsigned short* zb = qkvb + (size_t)Mv * N3;            //  8 MB  [8192][512]
  unsigned short* wxT = zb + (size_t)Mv * Cv;             // 1.5 MB [1536][512]
  unsigned short* weT = wxT + (size_t)N3 * Cv;            // 0.5 MB [512][512]

  transpose_f2b<<<dim3(N3 / 64, Cv / 64), 256, 0, stream>>>(w_xyz, wxT, Cv, N3);
  transpose_f2b<<<dim3(Cv / 64, Cv / 64), 256, 0, stream>>>(w_end, weT, Cv, Cv);
  ln_kernel<<<Mv / 4, 256, 0, stream>>>(x, gamma, beta, xnb);
  gemm_mfma<false, true><<<dim3(N3 / 128, Mv / 128), 256, 0, stream>>>(
      xnb, wxT, b_xyz, nullptr, nullptr, qkvb, Mv, N3, Cv);
  attn_mfma<<<dim3(Lv / 64, Hv, Bv), 256, 0, stream>>>(qkvb, zb);
  gemm_mfma<true, false><<<dim3(Cv / 128, Mv / 128), 256, 0, stream>>>(
      zb, weT, b_end, x, out, nullptr, Mv, Cv, Cv);
}

// Round 10
// 205.948 us; speedup vs baseline: 6.7450x; 1.0924x over previous
//
#include <hip/hip_runtime.h>
#include <hip/hip_bf16.h>
#include <math.h>

// Problem constants
constexpr int Bv = 4, Lv = 2048, Cv = 512, Hv = 8, CHv = 64;
constexpr int Mv = Bv * Lv;      // 8192 rows
constexpr int N3 = 3 * Cv;       // 1536
constexpr float EPSv = 1e-5f;
constexpr float K2v = 0.125f * 1.44269504089f; // scale * log2(e), exp2-domain softmax
constexpr int PSTR = 72;         // Ps row stride (16B-aligned rows for b128 reads)

typedef __attribute__((ext_vector_type(4))) float f32x4;
typedef __attribute__((ext_vector_type(8))) short bf16x8; // 8 bf16 in 4 VGPRs

__device__ inline unsigned short f2bf(float f) { // RNE float->bf16
  unsigned int u = __float_as_uint(f);
  unsigned int r = (u + 0x7fffu + ((u >> 16) & 1u)) >> 16;
  return (unsigned short)r;
}

// async global->LDS, 16B per lane; LDS dest = wave-uniform base + lane*16 (HW rule)
__device__ __forceinline__ void async_copy16(void* lp, const void* gp) {
  __builtin_amdgcn_global_load_lds(
      (const __attribute__((address_space(1))) void*)gp,
      (__attribute__((address_space(3))) void*)lp, 16, 0, 0);
}

// ---------------- LayerNorm: one wave per 512-float row; bf16 out ----------
__global__ __launch_bounds__(256) void ln_kernel(const float* __restrict__ x,
                                                 const float* __restrict__ gamma,
                                                 const float* __restrict__ beta,
                                                 unsigned short* __restrict__ xnb) {
  const int row = blockIdx.x * 4 + (threadIdx.x >> 6);
  const int lane = threadIdx.x & 63;
  const float4* xr = reinterpret_cast<const float4*>(x + (size_t)row * Cv);
  float4 v0 = xr[lane];
  float4 v1 = xr[lane + 64];
  float s = v0.x + v0.y + v0.z + v0.w + v1.x + v1.y + v1.z + v1.w;
  float q = v0.x * v0.x + v0.y * v0.y + v0.z * v0.z + v0.w * v0.w +
            v1.x * v1.x + v1.y * v1.y + v1.z * v1.z + v1.w * v1.w;
#pragma unroll
  for (int m = 1; m < 64; m <<= 1) {
    s += __shfl_xor(s, m, 64);
    q += __shfl_xor(q, m, 64);
  }
  const float mu = s * (1.0f / Cv);
  const float var = q * (1.0f / Cv) - mu * mu;
  const float rstd = rsqrtf(var + EPSv);
  const float4* g4 = reinterpret_cast<const float4*>(gamma);
  const float4* b4 = reinterpret_cast<const float4*>(beta);
  float4 ga = g4[lane], gb = g4[lane + 64];
  float4 ba = b4[lane], bb = b4[lane + 64];
  ushort4 u0, u1;
  u0.x = f2bf((v0.x - mu) * rstd * ga.x + ba.x);
  u0.y = f2bf((v0.y - mu) * rstd * ga.y + ba.y);
  u0.z = f2bf((v0.z - mu) * rstd * ga.z + ba.z);
  u0.w = f2bf((v0.w - mu) * rstd * ga.w + ba.w);
  u1.x = f2bf((v1.x - mu) * rstd * gb.x + bb.x);
  u1.y = f2bf((v1.y - mu) * rstd * gb.y + bb.y);
  u1.z = f2bf((v1.z - mu) * rstd * gb.z + bb.z);
  u1.w = f2bf((v1.w - mu) * rstd * gb.w + bb.w);
  ushort4* xo = reinterpret_cast<ushort4*>(xnb + (size_t)row * Cv);
  xo[lane] = u0;
  xo[lane + 64] = u1;
}

// ------------- transpose + fp32->bf16: out[c][r] = in[r][c] ----------------
__global__ __launch_bounds__(256) void transpose_f2b(const float* __restrict__ in,
                                                     unsigned short* __restrict__ out,
                                                     int R, int Cn) {
  __shared__ float Tl[64][65];
  const int t = threadIdx.x;
  const int tr = t >> 6, tc = t & 63;
  const int r0 = blockIdx.y * 64, c0 = blockIdx.x * 64;
#pragma unroll
  for (int i = 0; i < 16; ++i)
    Tl[tr + i * 4][tc] = in[(size_t)(r0 + tr + i * 4) * Cn + c0 + tc];
  __syncthreads();
#pragma unroll
  for (int i = 0; i < 16; ++i)
    out[(size_t)(c0 + tr + i * 4) * R + r0 + tc] = f2bf(Tl[tc][tr + i * 4]);
}

// ---------------- bf16 MFMA GEMM: C = A(MxK) * Bt^T + bias (+res) ----------
// HW-verified R6 structure. VOUT: columns >=1024 (the V third of QKV) are
// written TRANSPOSED to vT[b][h][ch][l] (4 consecutive rows -> one ushort4).
template <bool RES, bool OUTBF, bool VOUT>
__global__ __launch_bounds__(256) void gemm_mfma(const unsigned short* __restrict__ A,
                                                 const unsigned short* __restrict__ Bt,
                                                 const float* __restrict__ bias,
                                                 const float* __restrict__ res,
                                                 float* __restrict__ Cf,
                                                 unsigned short* __restrict__ Cb,
                                                 unsigned short* __restrict__ vTp,
                                                 int M, int N, int K) {
  __shared__ unsigned short Al[128 * 64]; // [row][64k], chunk-swizzled content
  __shared__ unsigned short Bl[128 * 64];
  const int t = threadIdx.x;
  const int l = t & 63, w = t >> 6;
  const int lm = l & 15, lq = l >> 4;
  const int m0 = blockIdx.y * 128, n0 = blockIdx.x * 128;
  const int rw0 = (w >> 1) * 64, cw0 = (w & 1) * 64; // wave's 64x64 sub-tile

  f32x4 acc[4][4];
#pragma unroll
  for (int mi = 0; mi < 4; ++mi)
#pragma unroll
    for (int ni = 0; ni < 4; ++ni) acc[mi][ni] = f32x4{0.f, 0.f, 0.f, 0.f};

  const int sr8 = l >> 3; // staging: lane's row-within-8
  const int sc = l & 7;   // lane's linear 16B chunk

  for (int k0 = 0; k0 < K; k0 += 64) {
#pragma unroll
    for (int j = 0; j < 4; ++j) {
      const int row = w * 32 + j * 8 + sr8;
      const int cs = sc ^ (row & 7); // pre-swizzled global chunk
      async_copy16(&Al[(w * 32 + j * 8) * 64],
                   A + (size_t)(m0 + row) * K + k0 + cs * 8);
      async_copy16(&Bl[(w * 32 + j * 8) * 64],
                   Bt + (size_t)(n0 + row) * K + k0 + cs * 8);
    }
    __syncthreads(); // vmcnt(0) drain -> tile visible

    bf16x8 af[4][2], bfr[4][2];
#pragma unroll
    for (int mi = 0; mi < 4; ++mi) {
      const int r = rw0 + mi * 16 + lm;
#pragma unroll
      for (int ks = 0; ks < 2; ++ks) {
        const int c = (ks * 4 + lq) ^ (r & 7); // swizzled read
        af[mi][ks] = *reinterpret_cast<const bf16x8*>(&Al[r * 64 + c * 8]);
      }
    }
#pragma unroll
    for (int ni = 0; ni < 4; ++ni) {
      const int r = cw0 + ni * 16 + lm;
#pragma unroll
      for (int ks = 0; ks < 2; ++ks) {
        const int c = (ks * 4 + lq) ^ (r & 7);
        bfr[ni][ks] = *reinterpret_cast<const bf16x8*>(&Bl[r * 64 + c * 8]);
      }
    }
#pragma unroll
    for (int ks = 0; ks < 2; ++ks)
#pragma unroll
      for (int mi = 0; mi < 4; ++mi)
#pragma unroll
        for (int ni = 0; ni < 4; ++ni)
          acc[mi][ni] = __builtin_amdgcn_mfma_f32_16x16x32_bf16(
              af[mi][ks], bfr[ni][ks], acc[mi][ni], 0, 0, 0);
    __syncthreads(); // reads done before next overwrite
  }

#pragma unroll
  for (int mi = 0; mi < 4; ++mi)
#pragma unroll
    for (int ni = 0; ni < 4; ++ni) {
      const int col = n0 + cw0 + ni * 16 + lm;
      const float bv = bias[col];
      if (VOUT && col >= 1024) {
        // V third -> vT[b][h][ch][l]; rows lq*4+0..3 are 4 consecutive l
        const int cc = col - 1024;
        const int hh = cc >> 6, chh = cc & 63;
        const int row0 = m0 + rw0 + mi * 16 + lq * 4;
        const int bb = row0 >> 11, l0 = row0 & 2047;
        ushort4 u;
        u.x = f2bf(acc[mi][ni][0] + bv);
        u.y = f2bf(acc[mi][ni][1] + bv);
        u.z = f2bf(acc[mi][ni][2] + bv);
        u.w = f2bf(acc[mi][ni][3] + bv);
        *reinterpret_cast<ushort4*>(
            &vTp[(((size_t)bb * 8 + hh) * 64 + chh) * 2048 + l0]) = u;
      } else {
#pragma unroll
        for (int r = 0; r < 4; ++r) {
          const int row = m0 + rw0 + mi * 16 + lq * 4 + r;
          float v = acc[mi][ni][r] + bv;
          if (RES) v += res[(size_t)row * N + col];
          if (OUTBF)
            Cb[(size_t)row * N + col] = f2bf(v);
          else
            Cf[(size_t)row * N + col] = v;
        }
      }
    }
}

// ---------------- bf16 MFMA flash attention v3 -----------------------------
// 8 waves, 128 q-rows/block, grid 512. Double-buffered K/V LDS staged via
// global_load_lds (1 instr/wave each, pre-swizzled source + XOR read — rule
// #21). SINGLE barrier per tile: {barrier; issue async(t+1); compute(t)} —
// write(t+1,buf Y) vs read(Y,t-1) separated by barrier(t); async drains at
// barrier(t+1) under a full compute phase (T14). Defer-max (T13, THR=8).
__global__ __launch_bounds__(512) void attn_mfma(const unsigned short* __restrict__ qkv,
                                                 const unsigned short* __restrict__ vT,
                                                 unsigned short* __restrict__ zb) {
  __shared__ unsigned short Ks[2][64 * 64]; // [key][ch], chunk-swizzled content
  __shared__ unsigned short Vt[2][64 * 64]; // [ch][key], chunk-swizzled content
  __shared__ unsigned short Ps[128 * PSTR]; // [qrow][key], per-wave 16-row slice

  const int t = threadIdx.x;
  const int l = t & 63, w = t >> 6; // 8 waves
  const int lm = l & 15, lq = l >> 4;

  const int f = blockIdx.x;
  const int n = (f & 7) * 64 + (f >> 3); // XCD swizzle (512 % 8 == 0)
  const int qt = n & 15, h = (n >> 4) & 7, b = n >> 7;
  const int q0 = qt * 128;

  const unsigned short* base = qkv + (size_t)b * Lv * N3;
  const unsigned short* vbase = vT + ((size_t)b * 8 + h) * 64 * 2048; // [ch][key]
  const int kcol = Cv + h * CHv;

  // Q fragment (B operand), hoisted
  bf16x8 qf0, qf1;
  {
    const unsigned short* qp = base + (size_t)(q0 + w * 16 + lm) * N3 + h * CHv + lq * 8;
    qf0 = *reinterpret_cast<const bf16x8*>(qp);
    qf1 = *reinterpret_cast<const bf16x8*>(qp + 32);
  }

  // staging: wave w covers rows 8w..8w+7 of both 64-row tiles; lane -> (row,chunk)
  const int sr8 = l >> 3;            // row within wave's 8
  const int scs = (l & 7) ^ sr8;     // pre-swizzled global chunk (row&7 == sr8)
  const int krow = w * 8 + sr8;

  f32x4 accO[4];
#pragma unroll
  for (int i = 0; i < 4; ++i) accO[i] = f32x4{0.f, 0.f, 0.f, 0.f};
  float m2 = -INFINITY; // running max (exp2 domain) for q = q0 + w*16 + lm
  float lsum = 0.f;

  // prologue: stage tile 0 into buf 0
  async_copy16(&Ks[0][w * 8 * 64], base + (size_t)krow * N3 + kcol + scs * 8);
  async_copy16(&Vt[0][w * 8 * 64], vbase + (size_t)krow * 2048 + 0 + scs * 8);

  for (int kt = 0; kt < Lv / 64; ++kt) {
    __syncthreads(); // drains async writes of buf[kt&1]; prev reads of it done

    if (kt + 1 < Lv / 64) {
      const int nb = (kt + 1) & 1;
      async_copy16(&Ks[nb][w * 8 * 64],
                   base + (size_t)((kt + 1) * 64 + krow) * N3 + kcol + scs * 8);
      async_copy16(&Vt[nb][w * 8 * 64],
                   vbase + (size_t)krow * 2048 + (kt + 1) * 64 + scs * 8);
    }

    const unsigned short* Kb = &Ks[kt & 1][0];
    const unsigned short* Vb = &Vt[kt & 1][0];

    // ---- S^T = K Q^T : 4 key-subtiles x 2 k-steps (swapped operands) ----
    f32x4 sacc[4];
#pragma unroll
    for (int s = 0; s < 4; ++s) {
      const int r = 16 * s + lm;
      bf16x8 kf0 = *reinterpret_cast<const bf16x8*>(&Kb[r * 64 + (lq ^ (lm & 7)) * 8]);
      bf16x8 kf1 = *reinterpret_cast<const bf16x8*>(&Kb[r * 64 + ((4 + lq) ^ (lm & 7)) * 8]);
      f32x4 zz = f32x4{0.f, 0.f, 0.f, 0.f};
      sacc[s] = __builtin_amdgcn_mfma_f32_16x16x32_bf16(kf0, qf0, zz, 0, 0, 0);
      sacc[s] = __builtin_amdgcn_mfma_f32_16x16x32_bf16(kf1, qf1, sacc[s], 0, 0, 0);
    }

    // ---- online softmax, exp2 domain, defer-max (THR=8) ----
    f32x4 m4 = __builtin_elementwise_max(__builtin_elementwise_max(sacc[0], sacc[1]),
                                         __builtin_elementwise_max(sacc[2], sacc[3]));
    float mx = fmaxf(fmaxf(m4[0], m4[1]), fmaxf(m4[2], m4[3]));
    mx = fmaxf(mx, __shfl_xor(mx, 16));
    mx = fmaxf(mx, __shfl_xor(mx, 32));
    const float mxs = mx * K2v;
    if (!__all(mxs - m2 <= 8.0f)) {
      const float m2n = fmaxf(m2, mxs);
      const float cf = exp2f(m2 - m2n);
      lsum *= cf;
      m2 = m2n;
#pragma unroll
      for (int r = 0; r < 4; ++r) {
        const float cfr = __shfl(cf, lq * 4 + r); // cf for q-row lq*4+r
        accO[0][r] *= cfr;
        accO[1][r] *= cfr;
        accO[2][r] *= cfr;
        accO[3][r] *= cfr;
      }
    }

    f32x4 ps[4];
#pragma unroll
    for (int s = 0; s < 4; ++s)
#pragma unroll
      for (int r = 0; r < 4; ++r)
        ps[s][r] = exp2f(sacc[s][r] * K2v - m2);

    // vectorized P write: keys 16s+4lq+[0..3] contiguous in Ps[q][key]
#pragma unroll
    for (int s = 0; s < 4; ++s) {
      uint2 pk;
      pk.x = (unsigned)f2bf(ps[s][0]) | ((unsigned)f2bf(ps[s][1]) << 16);
      pk.y = (unsigned)f2bf(ps[s][2]) | ((unsigned)f2bf(ps[s][3]) << 16);
      *reinterpret_cast<uint2*>(&Ps[(w * 16 + lm) * PSTR + 16 * s + 4 * lq]) = pk;
    }

    f32x4 s4 = (ps[0] + ps[1]) + (ps[2] + ps[3]);
    float psum = (s4[0] + s4[1]) + (s4[2] + s4[3]);
    psum += __shfl_xor(psum, 16);
    psum += __shfl_xor(psum, 32);
    lsum += psum;
    // same-wave Ps write->read below: DS in-order + compiler lgkmcnt

    // ---- O += P V (unswapped): A = Ps[q][key] b128, B = Vt chunk-swizzled ----
#pragma unroll
    for (int ks = 0; ks < 2; ++ks) {
      bf16x8 pf = *reinterpret_cast<const bf16x8*>(&Ps[(w * 16 + lm) * PSTR + ks * 32 + lq * 8]);
#pragma unroll
      for (int ot = 0; ot < 4; ++ot) {
        const int ch = 16 * ot + lm;
        bf16x8 vf = *reinterpret_cast<const bf16x8*>(
            &Vb[ch * 64 + ((4 * ks + lq) ^ (lm & 7)) * 8]);
        accO[ot] = __builtin_amdgcn_mfma_f32_16x16x32_bf16(pf, vf, accO[ot], 0, 0, 0);
      }
    }
  }

  // normalize and write z; accO row r is q-row lq*4+r; lsum lives at lane lm=q
#pragma unroll
  for (int r = 0; r < 4; ++r) {
    const float inv = 1.0f / __shfl(lsum, lq * 4 + r);
    const size_t row = (size_t)(b * Lv + q0 + w * 16 + lq * 4 + r);
#pragma unroll
    for (int ot = 0; ot < 4; ++ot)
      zb[row * Cv + h * CHv + 16 * ot + lm] = f2bf(accO[ot][r] * inv);
  }
}

extern "C" void kernel_launch(void* const* d_in, const int* in_sizes, int n_in,
                              void* d_out, int out_size, void* d_ws, size_t ws_size,
                              hipStream_t stream) {
  const float* x = (const float*)d_in[0];
  const float* gamma = (const float*)d_in[1];
  const float* beta = (const float*)d_in[2];
  const float* w_xyz = (const float*)d_in[3];
  const float* b_xyz = (const float*)d_in[4];
  const float* w_end = (const float*)d_in[5];
  const float* b_end = (const float*)d_in[6];
  float* out = (float*)d_out;

  // workspace (bf16 buffers)
  unsigned short* xnb = (unsigned short*)d_ws;            //  8 MB  [8192][512]
  unsigned short* qkvb = xnb + (size_t)Mv * Cv;           // 24 MB  [8192][1536] (Q,K used)
  unsigned short* zb = qkvb + (size_t)Mv * N3;            //  8 MB  [8192][512]
  unsigned short* wxT = zb + (size_t)Mv * Cv;             // 1.5 MB [1536][512]
  unsigned short* weT = wxT + (size_t)N3 * Cv;            // 0.5 MB [512][512]
  unsigned short* vTb = weT + (size_t)Cv * Cv;            //  8 MB  [4][8][64][2048]

  transpose_f2b<<<dim3(N3 / 64, Cv / 64), 256, 0, stream>>>(w_xyz, wxT, Cv, N3);
  transpose_f2b<<<dim3(Cv / 64, Cv / 64), 256, 0, stream>>>(w_end, weT, Cv, Cv);
  ln_kernel<<<Mv / 4, 256, 0, stream>>>(x, gamma, beta, xnb);
  gemm_mfma<false, true, true><<<dim3(N3 / 128, Mv / 128), 256, 0, stream>>>(
      xnb, wxT, b_xyz, nullptr, nullptr, qkvb, vTb, Mv, N3, Cv);
  attn_mfma<<<512, 512, 0, stream>>>(qkvb, vTb, zb);
  gemm_mfma<true, false, false><<<dim3(Cv / 128, Mv / 128), 256, 0, stream>>>(
      zb, weT, b_end, x, out, nullptr, nullptr, Mv, Cv, Cv);
}